// Round 8
// baseline (37.927 us; speedup 1.0000x reference)
//
#include <hip/hip_runtime.h>
#include <hip/hip_fp16.h>

typedef _Float16 half8  __attribute__((ext_vector_type(8)));
typedef _Float16 half4  __attribute__((ext_vector_type(4)));
typedef _Float16 h2v    __attribute__((ext_vector_type(2)));
typedef __fp16   fp16x2 __attribute__((ext_vector_type(2)));
typedef float    f32x4  __attribute__((ext_vector_type(4)));

#define B_N     2048
#define KLTOT   2048
#define NCHUNK  128
#define CHUNK_ROWS 16      // B_N / NCHUNK

// ---- workspace layout (dword slots) ----
#define WS_PART  0                         // 128*2048*2 = 524288
#define WS_W2F   (WS_PART + 524288)        // 2048*256 uints (f16-packed A-frags)
#define WS_W1H   (WS_W2F + 524288)         // 2048*16 uints (f16 pairs)
#define WS_B1H   (WS_W1H + 32768)          // 2048*16 uints
#define WS_W3H   (WS_B1H + 32768)          // 2048*8 uints (f16 pairs, j padded to 16)
#define WS_B2P   (WS_W3H + 16384)          // 2048*16 f32

// 5/5/4/4 h-slot packing: k-slot s = g*8+e maps to hidden unit hmap(g,e)
__device__ __forceinline__ int hmap(int g, int e) {
    return (g < 2) ? ((e < 5) ? g * 5 + e : -1)
                   : ((e < 4) ? 10 + (g - 2) * 4 + e : -1);
}

__device__ __forceinline__ unsigned int f16b(float f) {
    union { _Float16 h; unsigned short u; } c;
    c.h = (_Float16)f;
    return (unsigned int)c.u;
}

// ---------------- stats: partial sums over batch chunks ----------------
__global__ __launch_bounds__(256) void stats_partial(const float* __restrict__ x,
                                                     float* __restrict__ part) {
    int c4 = blockIdx.x * 256 + threadIdx.x;          // 0..511
    int chunk = blockIdx.y;                           // 0..127
    const float4* p = (const float4*)(x + (size_t)(chunk * CHUNK_ROWS) * KLTOT) + c4;
    float4 s = {0.f, 0.f, 0.f, 0.f}, s2 = {0.f, 0.f, 0.f, 0.f};
#pragma unroll
    for (int r = 0; r < CHUNK_ROWS; ++r) {
        float4 v = p[(size_t)r * (KLTOT / 4)];
        s.x += v.x; s.y += v.y; s.z += v.z; s.w += v.w;
        s2.x = fmaf(v.x, v.x, s2.x); s2.y = fmaf(v.y, v.y, s2.y);
        s2.z = fmaf(v.z, v.z, s2.z); s2.w = fmaf(v.w, v.w, s2.w);
    }
    float4* o = (float4*)(part + ((size_t)chunk * KLTOT + (size_t)c4 * 4) * 2);
    float4 o0 = {s.x, s2.x, s.y, s2.y};
    float4 o1 = {s.z, s2.z, s.w, s2.w};
    o[0] = o0;
    o[1] = o1;
}

// ---------------- prep: finalize stats + pack f16 weights (32 cols/block) ----------------
__global__ __launch_bounds__(256) void prep_w(
    const float* __restrict__ part,
    const float* __restrict__ W1, const float* __restrict__ b1,
    const float* __restrict__ W2, const float* __restrict__ b2,
    const float* __restrict__ W3,
    unsigned int* __restrict__ W2f,
    unsigned int* __restrict__ W1h, unsigned int* __restrict__ b1h,
    unsigned int* __restrict__ W3h, float* __restrict__ b2p)
{
    __shared__ float sW2[32 * 216];       // 27.6 KB
    __shared__ float red[256][2];
    __shared__ float smu[32], srs[32];
    const int tid = threadIdx.x;
    const int col0 = blockIdx.x * 32;

    // ---- stage W2 for 32 cols (coalesced) ----
    {
        const float4* src = (const float4*)(W2 + (size_t)col0 * 216);
        for (int t = tid; t < 32 * 54; t += 256)
            ((float4*)sW2)[t] = src[t];
    }

    // ---- stats partial-reduce (coalesced over cols) ----
    {
        const int col_l = tid & 31, cg = tid >> 5;    // 8 chunk-groups of 16
        const float2* pp = (const float2*)part;
        float s = 0.f, s2 = 0.f;
#pragma unroll 4
        for (int i = 0; i < 16; ++i) {
            float2 v = pp[(size_t)(cg * 16 + i) * KLTOT + col0 + col_l];
            s += v.x; s2 += v.y;
        }
        red[tid][0] = s; red[tid][1] = s2;
    }
    __syncthreads();

    if (tid < 32) {
        float S = 0.f, S2 = 0.f;
#pragma unroll
        for (int k = 0; k < 8; ++k) {
            S  += red[tid + 32 * k][0];
            S2 += red[tid + 32 * k][1];
        }
        float mu  = S / (float)B_N;
        float var = fmaxf(S2 / (float)B_N - mu * mu, 0.f);
        smu[tid] = mu;
        srs[tid] = 1.f / (sqrtf(var) + 1e-8f);
    }

    // ---- pack W2f (needs only sW2) ----
#pragma unroll 1
    for (int i = 0; i < 32; ++i) {
        int t = i * 256 + tid;
        int col = t >> 8, d = t & 255;
        unsigned int u[2];
#pragma unroll
        for (int h = 0; h < 2; ++h) {
            int idx = d * 2 + h;
            int gg = idx >> 7, j = (idx >> 3) & 15, e = idx & 7;
            int hh = hmap(gg, e);
            float v = (hh >= 0 && j < 12) ? sW2[col * 216 + hh * 12 + j] : 0.f;
            u[h] = f16b(v);
        }
        W2f[(size_t)(col0 + col) * 256 + d] = u[0] | (u[1] << 16);
    }
    __syncthreads();

    // ---- pack W1h/b1h (folded standardization), W3h, b2p ----
#pragma unroll
    for (int i = 0; i < 2; ++i) {
        int t = i * 256 + tid;
        int col = t >> 4, l = t & 15;
        int gg = l >> 2, q = l & 3;
        unsigned int wu = 0, bu = 0;
        if (q < 3) {
            float mu = smu[col], rs = srs[col];
            float w0 = 0.f, b0 = 0.f, w1v = 0.f, b1v = 0.f;
            int h0 = hmap(gg, q * 2), h1_ = hmap(gg, q * 2 + 1);
            if (h0 >= 0) {
                w0 = W1[(size_t)(col0 + col) * 18 + h0] * rs;
                b0 = fmaf(-mu, w0, b1[(size_t)(col0 + col) * 18 + h0]);
            }
            if (h1_ >= 0) {
                w1v = W1[(size_t)(col0 + col) * 18 + h1_] * rs;
                b1v = fmaf(-mu, w1v, b1[(size_t)(col0 + col) * 18 + h1_]);
            }
            wu = f16b(w0) | (f16b(w1v) << 16);
            bu = f16b(b0) | (f16b(b1v) << 16);
        }
        W1h[(size_t)(col0 + col) * 16 + l] = wu;
        b1h[(size_t)(col0 + col) * 16 + l] = bu;
    }
    {
        int col = tid >> 3, l = tid & 7;
        int j0 = 2 * l, j1 = 2 * l + 1;
        float v0 = (j0 < 12) ? W3[(size_t)(col0 + col) * 12 + j0] : 0.f;
        float v1 = (j1 < 12) ? W3[(size_t)(col0 + col) * 12 + j1] : 0.f;
        W3h[(size_t)(col0 + col) * 8 + l] = f16b(v0) | (f16b(v1) << 16);
    }
#pragma unroll
    for (int i = 0; i < 2; ++i) {
        int t = i * 256 + tid;
        int col = t >> 4, l = t & 15;
        b2p[(size_t)(col0 + col) * 16 + l] =
            (l < 12) ? b2[(size_t)(col0 + col) * 12 + l] : 0.f;
    }
}

// ---------------- main kernel: wave-per-column, 256-row tiles, dual chained MFMA ----------------
#define LJS 18           // lj stride (dwords)
#define CSC 292          // col stride (16*18 + 4 pad)

__global__ __launch_bounds__(512, 4) void mlp_mfma(
    const float* __restrict__ x,
    const unsigned int* __restrict__ W2f,
    const unsigned int* __restrict__ W1h, const unsigned int* __restrict__ b1h,
    const unsigned int* __restrict__ W3h, const float* __restrict__ b2p,
    const float* __restrict__ b3,
    float* __restrict__ out)
{
    __shared__ float tile[16 * CSC];      // 18.7 KB: [col][lj][rc]
    const int tid = threadIdx.x;
    const int kl0 = blockIdx.x * 16;
    const int b0  = blockIdx.y * 256;

    // ---- stage x [256 rows][16 cols] -> tile[c][r&15][r>>4] ----
#pragma unroll
    for (int p = 0; p < 2; ++p) {
        int idx = p * 512 + tid;
        int c4 = idx & 3, r = idx >> 2;
        f32x4 v = *(const f32x4*)(x + (size_t)(b0 + r) * KLTOT + kl0 + c4 * 4);
        int base = (r & 15) * LJS + (r >> 4);
#pragma unroll
        for (int e = 0; e < 4; ++e)
            tile[(c4 * 4 + e) * CSC + base] = v[e];
    }
    __syncthreads();

    const int w = tid >> 6, l = tid & 63;
    const int g = l >> 4, lj = l & 15;
    const h2v z2 = {(_Float16)0.f, (_Float16)0.f};
    const f32x4 zc = {0.f, 0.f, 0.f, 0.f};

    const int colA = kl0 + w, colB = kl0 + w + 8;

    // ---- both columns' constants issued up front (straight-line, no loop) ----
    union { uint4 u; half8 h; } afA, afB;
    afA.u = ((const uint4*)W2f)[(size_t)colA * 64 + g * 16 + lj];
    afB.u = ((const uint4*)W2f)[(size_t)colB * 64 + g * 16 + lj];
    union { uint4 u; h2v p[4]; } w1A, b1A, w1B, b1B;
    w1A.u = ((const uint4*)W1h)[(size_t)colA * 4 + g];
    w1B.u = ((const uint4*)W1h)[(size_t)colB * 4 + g];
    b1A.u = ((const uint4*)b1h)[(size_t)colA * 4 + g];
    b1B.u = ((const uint4*)b1h)[(size_t)colB * 4 + g];
    union { uint2 u; half4 h; } a2A, a2B;
    a2A.u = ((const uint2*)W3h)[(size_t)colA * 4 + g];
    a2B.u = ((const uint2*)W3h)[(size_t)colB * 4 + g];
    f32x4 b2A = ((const f32x4*)b2p)[(size_t)colA * 4 + g];
    f32x4 b2B = ((const f32x4*)b2p)[(size_t)colB * 4 + g];
    float b3A = b3[colA], b3B = b3[colB];

#define COLPASS(CLOC, AF, W1U, B1U, A2, B2R, B3V)                                   \
    {                                                                               \
        const float* xb = &tile[(CLOC) * CSC + lj * LJS];                           \
        float2 xv[8];                                                               \
        _Pragma("unroll")                                                           \
        for (int q = 0; q < 8; ++q) xv[q] = *(const float2*)(xb + 2 * q);           \
        float res[4];                                                               \
        _Pragma("unroll")                                                           \
        for (int rb = 0; rb < 16; ++rb) {                                           \
            float xsv = (rb & 1) ? xv[rb >> 1].y : xv[rb >> 1].x;                   \
            _Float16 xh = (_Float16)xsv;                                            \
            h2v x2 = {xh, xh};                                                      \
            union { h2v p[4]; half8 h; } bf;                                        \
            bf.p[0] = __builtin_elementwise_max(x2 * W1U.p[0] + B1U.p[0], z2);      \
            bf.p[1] = __builtin_elementwise_max(x2 * W1U.p[1] + B1U.p[1], z2);      \
            bf.p[2] = __builtin_elementwise_max(x2 * W1U.p[2] + B1U.p[2], z2);      \
            bf.p[3] = z2;                                                           \
            f32x4 acc = __builtin_amdgcn_mfma_f32_16x16x32_f16(AF.h, bf.h, B2R, 0, 0, 0); \
            union { fp16x2 c[2]; half4 h; } zf;                                     \
            zf.c[0] = __builtin_amdgcn_cvt_pkrtz(fmaxf(acc[0], 0.f), fmaxf(acc[1], 0.f)); \
            zf.c[1] = __builtin_amdgcn_cvt_pkrtz(fmaxf(acc[2], 0.f), fmaxf(acc[3], 0.f)); \
            f32x4 acc2 = __builtin_amdgcn_mfma_f32_16x16x16f16(A2.h, zf.h, zc, 0, 0, 0); \
            if ((rb >> 2) == g) res[rb & 3] = acc2[0] + B3V;                        \
        }                                                                           \
        float* tb = &tile[(CLOC) * CSC + lj * LJS + g * 4];                         \
        float2 r01 = {res[0], res[1]}, r23 = {res[2], res[3]};                      \
        *(float2*)tb = r01;                                                         \
        *(float2*)(tb + 2) = r23;                                                   \
    }

    COLPASS(w,     afA, w1A, b1A, a2A, b2A, b3A)
    COLPASS(w + 8, afB, w1B, b1B, a2B, b2B, b3B)
#undef COLPASS

    __syncthreads();

    // ---- coalesced store: out[r][c] from tile[c][r&15][r>>4] ----
#pragma unroll
    for (int p = 0; p < 2; ++p) {
        int idx = p * 512 + tid;
        int c4 = idx & 3, r = idx >> 2;
        int base = (r & 15) * LJS + (r >> 4);
        f32x4 v;
#pragma unroll
        for (int e = 0; e < 4; ++e)
            v[e] = tile[(c4 * 4 + e) * CSC + base];
        *(f32x4*)(out + (size_t)(b0 + r) * KLTOT + kl0 + c4 * 4) = v;
    }
}

extern "C" void kernel_launch(void* const* d_in, const int* in_sizes, int n_in,
                              void* d_out, int out_size, void* d_ws, size_t ws_size,
                              hipStream_t stream) {
    const float* x  = (const float*)d_in[0];
    const float* W1 = (const float*)d_in[1];
    const float* b1 = (const float*)d_in[2];
    const float* W2 = (const float*)d_in[3];
    const float* b2 = (const float*)d_in[4];
    const float* W3 = (const float*)d_in[5];
    const float* b3 = (const float*)d_in[6];
    float* out = (float*)d_out;

    float* ws = (float*)d_ws;
    float*        part = ws + WS_PART;
    unsigned int* W2f  = (unsigned int*)(ws + WS_W2F);
    unsigned int* W1h  = (unsigned int*)(ws + WS_W1H);
    unsigned int* b1h  = (unsigned int*)(ws + WS_B1H);
    unsigned int* W3h  = (unsigned int*)(ws + WS_W3H);
    float*        b2p  = ws + WS_B2P;

    stats_partial<<<dim3(2, NCHUNK),           256, 0, stream>>>(x, part);
    prep_w       <<<dim3(KLTOT / 32),          256, 0, stream>>>(part, W1, b1, W2, b2, W3,
                                                                 W2f, W1h, b1h, W3h, b2p);
    mlp_mfma     <<<dim3(KLTOT / 16, B_N / 256), 512, 0, stream>>>(
        x, W2f, W1h, b1h, W3h, b2p, b3, out);
}